// Round 19
// baseline (160.977 us; speedup 1.0000x reference)
//
#include <hip/hip_runtime.h>

#define NN 100000   // nodes
#define NE 800000   // edges
#define NF 500      // in features
#define NH 64       // hidden
#define NC 16       // classes
#define SCAN_B 98   // 98 * 1024 >= NN
#define G1TILES 782 // ceil(100000/128)
#define ROLEB 224   // hist role blocks fused into k_g1

typedef __attribute__((ext_vector_type(4))) float f32x4;
typedef __attribute__((ext_vector_type(8))) short bf16x8;  // 8 bf16 (4 VGPRs)

// raw RNE fp32->bf16 (proven; ~4 VALU, no NaN-canonicalization branch)
__device__ __forceinline__ unsigned int f2bf(float f) {
    union { float f; unsigned int u; } v; v.f = f;
    return (v.u + 0x7FFFu + ((v.u >> 16) & 1u)) >> 16;   // RNE
}
__device__ __forceinline__ unsigned int pkbf(float a, float b) {
    return f2bf(a) | (f2bf(b) << 16);
}
__device__ __forceinline__ float bfbits_lo(unsigned int u) { return __uint_as_float(u << 16); }
__device__ __forceinline__ float bfbits_hi(unsigned int u) { return __uint_as_float(u & 0xffff0000u); }

// async HBM->LDS, 16B per lane; LDS dest = wave-uniform base + lane*16 (linear)
#define GLOAD_LDS16(g, l) __builtin_amdgcn_global_load_lds(                      \
    (const __attribute__((address_space(1))) void*)(g),                          \
    (__attribute__((address_space(3))) void*)(l), 16, 0, 0)

// decode 8 fp8(e4m3) bytes of v, FMA into a[0..7] with weight w
__device__ __forceinline__ void acc_fp8x8(float* a, const uint2 v, const float w) {
    a[0] += w * __builtin_amdgcn_cvt_f32_fp8(v.x, 0);
    a[1] += w * __builtin_amdgcn_cvt_f32_fp8(v.x, 1);
    a[2] += w * __builtin_amdgcn_cvt_f32_fp8(v.x, 2);
    a[3] += w * __builtin_amdgcn_cvt_f32_fp8(v.x, 3);
    a[4] += w * __builtin_amdgcn_cvt_f32_fp8(v.y, 0);
    a[5] += w * __builtin_amdgcn_cvt_f32_fp8(v.y, 1);
    a[6] += w * __builtin_amdgcn_cvt_f32_fp8(v.y, 2);
    a[7] += w * __builtin_amdgcn_cvt_f32_fp8(v.y, 3);
}

// device-scope grid barrier: all SCAN_B blocks co-resident (98 blocks x 16 waves)
__device__ __forceinline__ void gridbar(int* cnt, int target) {
    __syncthreads();
    if (threadIdx.x == 0) {
        __threadfence();
        atomicAdd(cnt, 1);
        while (__hip_atomic_load(cnt, __ATOMIC_ACQUIRE, __HIP_MEMORY_SCOPE_AGENT) < target) {}
    }
    __syncthreads();
}

// ---------------- zero cursor/deg + barrier counter ----------------
__global__ __launch_bounds__(256) void k_zero(int4* __restrict__ p) {
    int i = blockIdx.x * 256 + threadIdx.x;          // 25001 int4: cursor + barcnt pad
    if (i < NN / 4 + 1) p[i] = make_int4(0, 0, 0, 0);
}

// ---------------- fused scan: scanA + scanC via grid barrier (proven r9/r10) ----------------
__global__ __launch_bounds__(1024) void k_scan(int* __restrict__ deg_cursor, int* __restrict__ bsum,
                                               int* __restrict__ start, int* __restrict__ barcnt) {
    __shared__ int s[1024];
    __shared__ int bs[128];
    const int t = threadIdx.x, b = blockIdx.x;
    const int i = b * 1024 + t;
    int d = (i < NN) ? deg_cursor[i] : 0;
    s[t] = d;
    __syncthreads();
    // block-local inclusive scan (stays in LDS across the barrier)
    for (int off = 1; off < 1024; off <<= 1) {
        int u = (t >= off) ? s[t - off] : 0;
        __syncthreads();
        s[t] += u;
        __syncthreads();
    }
    if (t == 1023) bsum[b] = s[1023];
    gridbar(barcnt, SCAN_B);                 // all bsum visible
    // scan the 98 block sums (each block locally)
    if (t < 128) bs[t] = (t < SCAN_B) ? bsum[t] : 0;
    __syncthreads();
    for (int off = 1; off < 128; off <<= 1) {
        int u = 0;
        if (t < 128 && t >= off) u = bs[t - off];
        __syncthreads();
        if (t < 128 && t >= off) bs[t] += u;
        __syncthreads();
    }
    int base = (b == 0) ? 0 : bs[b - 1];
    if (i < NN) {
        int ex = base + s[t] - d;
        start[i] = ex;
        deg_cursor[i] = ex;                  // becomes scatter cursor
    }
    if (b == SCAN_B - 1 && t == 0) start[NN] = bs[SCAN_B - 1];   // = NE
}

// ---------------- scatter edges into CSR order (full grid) ----------------
__global__ void k_scatter(const int* __restrict__ src, const int* __restrict__ dst,
                          const float* __restrict__ ew, int* __restrict__ cursor,
                          int2* __restrict__ edges) {
    int e = blockIdx.x * 256 + threadIdx.x;
    if (e < NE) {
        int p = atomicAdd(&cursor[dst[e]], 1);
        edges[p] = make_int2(src[e], __float_as_int(ew[e]));
    }
}

// ---------------- GEMM1 (full, MFMA bf16) + fused hist role; fp8 h1 out ----------------
__global__ __launch_bounds__(256) void k_g1(const float* __restrict__ x,
                                            const float* __restrict__ W1,
                                            unsigned char* __restrict__ h1f,
                                            const int* __restrict__ dst, int* __restrict__ deg) {
    __shared__ float xs[128 * 64];           // 32 KB fp32 (reused as fp8 staging in epilogue)
    __shared__ unsigned short ws[64 * 64];   // 8 KB bf16
    const int bid = blockIdx.x, tid = threadIdx.x;
    if (bid >= G1TILES) {                    // hist role
        int rb = bid - G1TILES;
        for (int e = rb * 256 + tid; e < NE; e += ROLEB * 256)
            atomicAdd(&deg[dst[e]], 1);
        return;
    }
    const int lane = tid & 63;
    const int wv   = tid >> 6;
    const int row0 = bid * 128;

    f32x4 acc[2][4];
#pragma unroll
    for (int i = 0; i < 2; ++i)
#pragma unroll
        for (int j = 0; j < 4; ++j) acc[i][j] = (f32x4){0.f, 0.f, 0.f, 0.f};

    const int lr    = lane >> 4;         // row within issue group (0..3)
    const int lsl   = (lane & 15) >> 1;  // 8-float slot (0..7)
    const int lhalf = lane & 1;          // half-slot (0..1)
    const long maxidx = (long)NN * NF - 4;

    for (int kt = 0; kt < 8; ++kt) {
        const int k0 = kt * 64;
#pragma unroll
        for (int i = 0; i < 8; ++i) {
            int r  = wv * 32 + i * 4 + lr;
            int gm = row0 + r; if (gm >= NN) gm = NN - 1;
            long gi = (long)gm * NF + k0 + ((lsl ^ (r & 7)) << 3) + (lhalf << 2);
            if (gi > maxidx) gi = maxidx;                    // clamp; values killed by W=0
            GLOAD_LDS16(x + gi, xs + (wv * 32 + i * 4) * 64);
        }
#pragma unroll
        for (int p = 0; p < 2; ++p) {
            int u  = tid + p * 256;
            int n  = u & 63, sl = u >> 6;
            int gk = k0 + sl * 8;
            float e[8];
#pragma unroll
            for (int j = 0; j < 8; ++j)
                e[j] = (gk + j < NF) ? W1[(long)(gk + j) * NH + n] : 0.f;
            uint4 pk;
            pk.x = pkbf(e[0], e[1]);
            pk.y = pkbf(e[2], e[3]);
            pk.z = pkbf(e[4], e[5]);
            pk.w = pkbf(e[6], e[7]);
            *(uint4*)(ws + n * 64 + (sl ^ (n & 7)) * 8) = pk;
        }
        __syncthreads();
#pragma unroll
        for (int ks = 0; ks < 2; ++ks) {
            const int kg = ks * 4 + (lane >> 4);
            bf16x8 af[2], bfr[4];
#pragma unroll
            for (int i = 0; i < 2; ++i) {
                int r = wv * 32 + i * 16 + (lane & 15);
                const float* srcp = xs + r * 64 + ((kg ^ (r & 7)) << 3);
                f32x4 lo = *(const f32x4*)(srcp);
                f32x4 hi = *(const f32x4*)(srcp + 4);
                uint4 pk;
                pk.x = pkbf(lo[0], lo[1]);
                pk.y = pkbf(lo[2], lo[3]);
                pk.z = pkbf(hi[0], hi[1]);
                pk.w = pkbf(hi[2], hi[3]);
                af[i] = *(bf16x8*)&pk;
            }
#pragma unroll
            for (int j = 0; j < 4; ++j) {
                int n = j * 16 + (lane & 15);
                bfr[j] = *(const bf16x8*)(ws + n * 64 + (kg ^ (n & 7)) * 8);
            }
#pragma unroll
            for (int i = 0; i < 2; ++i)
#pragma unroll
                for (int j = 0; j < 4; ++j)
                    acc[i][j] = __builtin_amdgcn_mfma_f32_16x16x32_bf16(af[i], bfr[j], acc[i][j], 0, 0, 0);
        }
        __syncthreads();
    }
    // epilogue: fp8(e4m3) rows staged via LDS (xs reused), then coalesced 16B stores
    unsigned char* xb = (unsigned char*)xs;
    const int c = lane & 15;
#pragma unroll
    for (int i = 0; i < 2; ++i) {
#pragma unroll
        for (int q = 0; q < 4; ++q) {
            int r = wv * 32 + i * 16 + (lane >> 4) * 4 + q;   // row within tile
            int pk01 = __builtin_amdgcn_cvt_pk_fp8_f32(acc[i][0][q], acc[i][1][q], 0, false);
            int pk23 = __builtin_amdgcn_cvt_pk_fp8_f32(acc[i][2][q], acc[i][3][q], 0, false);
            xb[r * 64 + 0 * 16 + c] = (unsigned char)(pk01 & 0xff);
            xb[r * 64 + 1 * 16 + c] = (unsigned char)((pk01 >> 8) & 0xff);
            xb[r * 64 + 2 * 16 + c] = (unsigned char)(pk23 & 0xff);
            xb[r * 64 + 3 * 16 + c] = (unsigned char)((pk23 >> 8) & 0xff);
        }
    }
    __syncthreads();
    {
        int rr = tid >> 1, off = (tid & 1) * 32;
        int gm = row0 + rr;
        if (gm < NN) {
            uint4 a = *(uint4*)(xb + rr * 64 + off);
            uint4 b = *(uint4*)(xb + rr * 64 + off + 16);
            *(uint4*)(h1f + (long)gm * 64 + off)      = a;
            *(uint4*)(h1f + (long)gm * 64 + off + 16) = b;
        }
    }
}

// ---------------- Layer 1 fused: spmm1(fp8, 4-deep gather) + bias + ReLU + gemm2 ----------------
// 2 nodes/wave x 4 edge-slots x 8 feature-lanes; per round 4 records
// loaded branch-free (OOB clamped to p, weight zeroed) -> 4 gathers in flight.
__global__ __launch_bounds__(256) void k_l1(const int* __restrict__ start,
                                            const int2* __restrict__ edges,
                                            const unsigned char* __restrict__ h1f,
                                            const float* __restrict__ b1,
                                            const float* __restrict__ W2,
                                            unsigned short* __restrict__ h2b) {
    __shared__ float w2s[NH * NC];           // 4 KB
    const int tid = threadIdx.x;
    const float4 w2stage = *(const float4*)(W2 + tid * 4);   // 256 x 4 = 1024 floats

    const int lane = tid & 63;
    const int wid  = ((blockIdx.x * 256 + tid) >> 6) * 2 + (lane >> 5);  // 2 nodes/wave
    const int fo   = lane & 7;               // feature octet
    const int es   = (lane >> 3) & 3;        // edge slot (0..3)

    const int s = start[wid], e = start[wid + 1];
    float a[8] = {0.f, 0.f, 0.f, 0.f, 0.f, 0.f, 0.f, 0.f};
    int p = s + es;
    while (p < e) {
        const int i1 = p + 4, i2 = p + 8, i3 = p + 12;
        const bool b1c = i1 < e, b2c = i2 < e, b3c = i3 < e;
        const int2 r0 = edges[p];
        const int2 r1 = edges[b1c ? i1 : p];
        const int2 r2 = edges[b2c ? i2 : p];
        const int2 r3 = edges[b3c ? i3 : p];
        const uint2 v0 = *(const uint2*)(h1f + (long)r0.x * 64 + fo * 8);
        const uint2 v1 = *(const uint2*)(h1f + (long)r1.x * 64 + fo * 8);
        const uint2 v2 = *(const uint2*)(h1f + (long)r2.x * 64 + fo * 8);
        const uint2 v3 = *(const uint2*)(h1f + (long)r3.x * 64 + fo * 8);
        acc_fp8x8(a, v0, __int_as_float(r0.y));
        acc_fp8x8(a, v1, b1c ? __int_as_float(r1.y) : 0.f);
        acc_fp8x8(a, v2, b2c ? __int_as_float(r2.y) : 0.f);
        acc_fp8x8(a, v3, b3c ? __int_as_float(r3.y) : 0.f);
        p += 16;
    }
    // W2 -> LDS (deferred staging: hidden under the gather loop)
    *(float4*)(w2s + tid * 4) = w2stage;
    __syncthreads();
    // reduce over the 4 edge slots (xor 8,16: stays within the 32-lane node group)
#pragma unroll
    for (int m = 8; m <= 16; m <<= 1)
#pragma unroll
        for (int j = 0; j < 8; ++j) a[j] += __shfl_xor(a[j], m, 64);
    // bias + ReLU (all lanes hold full sums of their feature octet)
    const float4 ba = *(const float4*)(b1 + fo * 8);
    const float4 bb = *(const float4*)(b1 + fo * 8 + 4);
    float r[8];
    r[0] = fmaxf(a[0] + ba.x, 0.f); r[1] = fmaxf(a[1] + ba.y, 0.f);
    r[2] = fmaxf(a[2] + ba.z, 0.f); r[3] = fmaxf(a[3] + ba.w, 0.f);
    r[4] = fmaxf(a[4] + bb.x, 0.f); r[5] = fmaxf(a[5] + bb.y, 0.f);
    r[6] = fmaxf(a[6] + bb.z, 0.f); r[7] = fmaxf(a[7] + bb.w, 0.f);
    // fused gemm2: this lane contributes its 8 features to outputs es*4..es*4+3
    float p0 = 0.f, p1 = 0.f, p2 = 0.f, p3 = 0.f;
#pragma unroll
    for (int j = 0; j < 8; ++j) {
        const f32x4 wv = *(const f32x4*)(w2s + (fo * 8 + j) * NC + es * 4);
        p0 += r[j] * wv[0]; p1 += r[j] * wv[1];
        p2 += r[j] * wv[2]; p3 += r[j] * wv[3];
    }
    // reduce over the 8 feature lanes (xor 1,2,4)
#pragma unroll
    for (int m = 1; m <= 4; m <<= 1) {
        p0 += __shfl_xor(p0, m, 64); p1 += __shfl_xor(p1, m, 64);
        p2 += __shfl_xor(p2, m, 64); p3 += __shfl_xor(p3, m, 64);
    }
    if (fo == 0) {
        uint2 pk;
        pk.x = pkbf(p0, p1);
        pk.y = pkbf(p2, p3);
        *(uint2*)(h2b + (long)wid * NC + es * 4) = pk;
    }
}

// ---------------- SpMM2 + bias: 4 nodes/wave x 4 edge-slots, 4-deep gather ----------------
__global__ __launch_bounds__(256) void k_spmm2(const int* __restrict__ start,
                                               const int2* __restrict__ edges,
                                               const unsigned short* __restrict__ h2b,
                                               const float* __restrict__ b2,
                                               float* __restrict__ out) {
    const int lane = threadIdx.x & 63;
    const int wid  = ((blockIdx.x * 256 + threadIdx.x) >> 6) * 4 + (lane >> 4);  // 4 nodes/wave
    const int es   = (lane >> 2) & 3;        // edge slot (0..3)
    const int f4   = lane & 3;               // feature quad
    const int s = start[wid], e = start[wid + 1];
    float4 acc = make_float4(0.f, 0.f, 0.f, 0.f);
    int p = s + es;
    while (p < e) {
        const int i1 = p + 4, i2 = p + 8, i3 = p + 12;
        const bool b1c = i1 < e, b2c = i2 < e, b3c = i3 < e;
        const int2 r0 = edges[p];
        const int2 r1 = edges[b1c ? i1 : p];
        const int2 r2 = edges[b2c ? i2 : p];
        const int2 r3 = edges[b3c ? i3 : p];
        const uint2 v0 = *(const uint2*)(h2b + (long)r0.x * NC + f4 * 4);
        const uint2 v1 = *(const uint2*)(h2b + (long)r1.x * NC + f4 * 4);
        const uint2 v2 = *(const uint2*)(h2b + (long)r2.x * NC + f4 * 4);
        const uint2 v3 = *(const uint2*)(h2b + (long)r3.x * NC + f4 * 4);
        const float w0 = __int_as_float(r0.y);
        const float w1 = b1c ? __int_as_float(r1.y) : 0.f;
        const float w2 = b2c ? __int_as_float(r2.y) : 0.f;
        const float w3 = b3c ? __int_as_float(r3.y) : 0.f;
        acc.x += w0 * bfbits_lo(v0.x); acc.y += w0 * bfbits_hi(v0.x);
        acc.z += w0 * bfbits_lo(v0.y); acc.w += w0 * bfbits_hi(v0.y);
        acc.x += w1 * bfbits_lo(v1.x); acc.y += w1 * bfbits_hi(v1.x);
        acc.z += w1 * bfbits_lo(v1.y); acc.w += w1 * bfbits_hi(v1.y);
        acc.x += w2 * bfbits_lo(v2.x); acc.y += w2 * bfbits_hi(v2.x);
        acc.z += w2 * bfbits_lo(v2.y); acc.w += w2 * bfbits_hi(v2.y);
        acc.x += w3 * bfbits_lo(v3.x); acc.y += w3 * bfbits_hi(v3.x);
        acc.z += w3 * bfbits_lo(v3.y); acc.w += w3 * bfbits_hi(v3.y);
        p += 16;
    }
    // reduce over the 4 edge slots (xor 4,8: stays within the 16-lane node group)
#pragma unroll
    for (int m = 4; m <= 8; m <<= 1) {
        acc.x += __shfl_xor(acc.x, m, 64); acc.y += __shfl_xor(acc.y, m, 64);
        acc.z += __shfl_xor(acc.z, m, 64); acc.w += __shfl_xor(acc.w, m, 64);
    }
    if (es == 0) {
        const float4 b = *(const float4*)(b2 + f4 * 4);
        float4 r;
        r.x = acc.x + b.x; r.y = acc.y + b.y;
        r.z = acc.z + b.z; r.w = acc.w + b.w;
        *(float4*)(out + (long)wid * NC + f4 * 4) = r;
    }
}

extern "C" void kernel_launch(void* const* d_in, const int* in_sizes, int n_in,
                              void* d_out, int out_size, void* d_ws, size_t ws_size,
                              hipStream_t stream) {
    const float* x   = (const float*)d_in[0];
    const float* W1  = (const float*)d_in[1];
    const float* b1  = (const float*)d_in[2];
    const float* W2  = (const float*)d_in[3];
    const float* b2  = (const float*)d_in[4];
    const float* ew  = (const float*)d_in[5];
    const int*   src = (const int*)d_in[6];
    const int*   dst = (const int*)d_in[7];
    float* out = (float*)d_out;

    // workspace layout (<40 MB)
    char* w = (char*)d_ws;
    unsigned char*  h1f = (unsigned char*)(w + 0);           // 6.4 MB fp8 x@W1
    unsigned short* h2b = (unsigned short*)(w + 25600000);   // 3.2 MB bf16 (relu layer1)@W2
    int*   bsum   = (int*) (w + 32000000);                   // 98 ints
    int*   startp = (int*) (w + 32001024);                   // 100001 ints
    int*   cursor = (int*) (w + 32402048);                   // 100000 ints (deg -> cursor)
    int*   barcnt = (int*) (w + 32802048);                   // grid-barrier counter (zeroed each launch)
    int2*  edges  = (int2*)(w + 32803072);                   // 6.4 MB (src, w) records

    k_zero   <<<(NN / 4 + 1 + 255) / 256, 256, 0, stream>>>((int4*)cursor);
    k_g1     <<<G1TILES + ROLEB, 256, 0, stream>>>(x, W1, h1f, dst, cursor);
    k_scan   <<<SCAN_B, 1024, 0, stream>>>(cursor, bsum, startp, barcnt);
    k_scatter<<<(NE + 255) / 256, 256, 0, stream>>>(src, dst, ew, cursor, edges);
    k_l1     <<<(NN / 2 * 64) / 256, 256, 0, stream>>>(startp, edges, h1f, b1, W2, h2b);
    k_spmm2  <<<(NN / 4 * 64) / 256, 256, 0, stream>>>(startp, edges, h2b, b2, out);
}

// Round 20
// 153.378 us; speedup vs baseline: 1.0495x; 1.0495x over previous
//
#include <hip/hip_runtime.h>

#define NN 100000   // nodes
#define NE 800000   // edges
#define NF 500      // in features
#define NH 64       // hidden
#define NC 16       // classes
#define SCAN_B 98   // 98 * 1024 >= NN
#define G1TILES 782 // ceil(100000/128)
#define ROLEB 224   // scatter role blocks fused into k_g1

typedef __attribute__((ext_vector_type(4))) float f32x4;
typedef __attribute__((ext_vector_type(8))) short bf16x8;  // 8 bf16 (4 VGPRs)

// raw RNE fp32->bf16 (proven; ~4 VALU, no NaN-canonicalization branch)
__device__ __forceinline__ unsigned int f2bf(float f) {
    union { float f; unsigned int u; } v; v.f = f;
    return (v.u + 0x7FFFu + ((v.u >> 16) & 1u)) >> 16;   // RNE
}
__device__ __forceinline__ unsigned int pkbf(float a, float b) {
    return f2bf(a) | (f2bf(b) << 16);
}
__device__ __forceinline__ float bfbits_lo(unsigned int u) { return __uint_as_float(u << 16); }
__device__ __forceinline__ float bfbits_hi(unsigned int u) { return __uint_as_float(u & 0xffff0000u); }

// async HBM->LDS, 16B per lane; LDS dest = wave-uniform base + lane*16 (linear)
#define GLOAD_LDS16(g, l) __builtin_amdgcn_global_load_lds(                      \
    (const __attribute__((address_space(1))) void*)(g),                          \
    (__attribute__((address_space(3))) void*)(l), 16, 0, 0)

// decode 8 fp8(e4m3) bytes of v, FMA into a[0..7] with weight w
__device__ __forceinline__ void acc_fp8x8(float* a, const uint2 v, const float w) {
    a[0] += w * __builtin_amdgcn_cvt_f32_fp8(v.x, 0);
    a[1] += w * __builtin_amdgcn_cvt_f32_fp8(v.x, 1);
    a[2] += w * __builtin_amdgcn_cvt_f32_fp8(v.x, 2);
    a[3] += w * __builtin_amdgcn_cvt_f32_fp8(v.x, 3);
    a[4] += w * __builtin_amdgcn_cvt_f32_fp8(v.y, 0);
    a[5] += w * __builtin_amdgcn_cvt_f32_fp8(v.y, 1);
    a[6] += w * __builtin_amdgcn_cvt_f32_fp8(v.y, 2);
    a[7] += w * __builtin_amdgcn_cvt_f32_fp8(v.y, 3);
}

// ---------------- zero cursor/deg ----------------
__global__ __launch_bounds__(256) void k_zero(int4* __restrict__ p) {
    int i = blockIdx.x * 256 + threadIdx.x;          // 25000 int4 = 100000 ints
    if (i < NN / 4) p[i] = make_int4(0, 0, 0, 0);
}

// ---------------- degree histogram (standalone; runs before the scans) ----------------
__global__ void k_hist(const int* __restrict__ dst, int* __restrict__ deg) {
    int e = blockIdx.x * 256 + threadIdx.x;
    if (e < NE) atomicAdd(&deg[dst[e]], 1);
}

// ---------------- scan stage A: per-block sums ----------------
__global__ __launch_bounds__(1024) void k_scanA(const int* __restrict__ deg, int* __restrict__ bsum) {
    __shared__ int s[1024];
    int t = threadIdx.x, i = blockIdx.x * 1024 + t;
    s[t] = (i < NN) ? deg[i] : 0;
    __syncthreads();
    for (int off = 512; off > 0; off >>= 1) {
        if (t < off) s[t] += s[t + off];
        __syncthreads();
    }
    if (t == 0) bsum[blockIdx.x] = s[0];
}

// ---------------- scan stage C: bsum-scan + local scan ----------------
__global__ __launch_bounds__(1024) void k_scanC(const int* __restrict__ deg, const int* __restrict__ bsum,
                                                int* __restrict__ start, int* __restrict__ cursor) {
    __shared__ int s[1024];
    __shared__ int bs[128];
    int t = threadIdx.x, i = blockIdx.x * 1024 + t;
    if (t < 128) bs[t] = (t < SCAN_B) ? bsum[t] : 0;
    int d = (i < NN) ? deg[i] : 0;
    s[t] = d;
    __syncthreads();
    for (int off = 1; off < 128; off <<= 1) {
        int u = 0;
        if (t < 128 && t >= off) u = bs[t - off];
        __syncthreads();
        if (t < 128 && t >= off) bs[t] += u;
        __syncthreads();
    }
    for (int off = 1; off < 1024; off <<= 1) {
        int u = (t >= off) ? s[t - off] : 0;
        __syncthreads();
        s[t] += u;
        __syncthreads();
    }
    int base = (blockIdx.x == 0) ? 0 : bs[blockIdx.x - 1];
    if (i < NN) {
        int ex = base + s[t] - d;
        start[i] = ex;
        cursor[i] = ex;
    }
    if (blockIdx.x == SCAN_B - 1 && t == 0) start[NN] = bs[SCAN_B - 1];   // = NE
}

// ---------------- GEMM1 (full, MFMA bf16) + fused SCATTER role; fp8 h1 out ----------------
__global__ __launch_bounds__(256) void k_g1(const float* __restrict__ x,
                                            const float* __restrict__ W1,
                                            unsigned char* __restrict__ h1f,
                                            const int* __restrict__ src, const int* __restrict__ dst,
                                            const float* __restrict__ ew,
                                            int* __restrict__ cursor, int2* __restrict__ edges) {
    __shared__ float xs[128 * 64];           // 32 KB fp32 (reused as fp8 staging in epilogue)
    __shared__ unsigned short ws[64 * 64];   // 8 KB bf16
    const int bid = blockIdx.x, tid = threadIdx.x;
    if (bid >= G1TILES) {                    // scatter role (CSR cursors ready before launch)
        int rb = bid - G1TILES;
        for (int e = rb * 256 + tid; e < NE; e += ROLEB * 256) {
            int p = atomicAdd(&cursor[dst[e]], 1);
            edges[p] = make_int2(src[e], __float_as_int(ew[e]));
        }
        return;
    }
    const int lane = tid & 63;
    const int wv   = tid >> 6;
    const int row0 = bid * 128;

    f32x4 acc[2][4];
#pragma unroll
    for (int i = 0; i < 2; ++i)
#pragma unroll
        for (int j = 0; j < 4; ++j) acc[i][j] = (f32x4){0.f, 0.f, 0.f, 0.f};

    const int lr    = lane >> 4;         // row within issue group (0..3)
    const int lsl   = (lane & 15) >> 1;  // 8-float slot (0..7)
    const int lhalf = lane & 1;          // half-slot (0..1)
    const long maxidx = (long)NN * NF - 4;

    for (int kt = 0; kt < 8; ++kt) {
        const int k0 = kt * 64;
#pragma unroll
        for (int i = 0; i < 8; ++i) {
            int r  = wv * 32 + i * 4 + lr;
            int gm = row0 + r; if (gm >= NN) gm = NN - 1;
            long gi = (long)gm * NF + k0 + ((lsl ^ (r & 7)) << 3) + (lhalf << 2);
            if (gi > maxidx) gi = maxidx;                    // clamp; values killed by W=0
            GLOAD_LDS16(x + gi, xs + (wv * 32 + i * 4) * 64);
        }
#pragma unroll
        for (int p = 0; p < 2; ++p) {
            int u  = tid + p * 256;
            int n  = u & 63, sl = u >> 6;
            int gk = k0 + sl * 8;
            float e[8];
#pragma unroll
            for (int j = 0; j < 8; ++j)
                e[j] = (gk + j < NF) ? W1[(long)(gk + j) * NH + n] : 0.f;
            uint4 pk;
            pk.x = pkbf(e[0], e[1]);
            pk.y = pkbf(e[2], e[3]);
            pk.z = pkbf(e[4], e[5]);
            pk.w = pkbf(e[6], e[7]);
            *(uint4*)(ws + n * 64 + (sl ^ (n & 7)) * 8) = pk;
        }
        __syncthreads();
#pragma unroll
        for (int ks = 0; ks < 2; ++ks) {
            const int kg = ks * 4 + (lane >> 4);
            bf16x8 af[2], bfr[4];
#pragma unroll
            for (int i = 0; i < 2; ++i) {
                int r = wv * 32 + i * 16 + (lane & 15);
                const float* srcp = xs + r * 64 + ((kg ^ (r & 7)) << 3);
                f32x4 lo = *(const f32x4*)(srcp);
                f32x4 hi = *(const f32x4*)(srcp + 4);
                uint4 pk;
                pk.x = pkbf(lo[0], lo[1]);
                pk.y = pkbf(lo[2], lo[3]);
                pk.z = pkbf(hi[0], hi[1]);
                pk.w = pkbf(hi[2], hi[3]);
                af[i] = *(bf16x8*)&pk;
            }
#pragma unroll
            for (int j = 0; j < 4; ++j) {
                int n = j * 16 + (lane & 15);
                bfr[j] = *(const bf16x8*)(ws + n * 64 + (kg ^ (n & 7)) * 8);
            }
#pragma unroll
            for (int i = 0; i < 2; ++i)
#pragma unroll
                for (int j = 0; j < 4; ++j)
                    acc[i][j] = __builtin_amdgcn_mfma_f32_16x16x32_bf16(af[i], bfr[j], acc[i][j], 0, 0, 0);
        }
        __syncthreads();
    }
    // epilogue: fp8(e4m3) rows staged via LDS (xs reused), then coalesced 16B stores
    unsigned char* xb = (unsigned char*)xs;
    const int c = lane & 15;
#pragma unroll
    for (int i = 0; i < 2; ++i) {
#pragma unroll
        for (int q = 0; q < 4; ++q) {
            int r = wv * 32 + i * 16 + (lane >> 4) * 4 + q;   // row within tile
            int pk01 = __builtin_amdgcn_cvt_pk_fp8_f32(acc[i][0][q], acc[i][1][q], 0, false);
            int pk23 = __builtin_amdgcn_cvt_pk_fp8_f32(acc[i][2][q], acc[i][3][q], 0, false);
            xb[r * 64 + 0 * 16 + c] = (unsigned char)(pk01 & 0xff);
            xb[r * 64 + 1 * 16 + c] = (unsigned char)((pk01 >> 8) & 0xff);
            xb[r * 64 + 2 * 16 + c] = (unsigned char)(pk23 & 0xff);
            xb[r * 64 + 3 * 16 + c] = (unsigned char)((pk23 >> 8) & 0xff);
        }
    }
    __syncthreads();
    {
        int rr = tid >> 1, off = (tid & 1) * 32;
        int gm = row0 + rr;
        if (gm < NN) {
            uint4 a = *(uint4*)(xb + rr * 64 + off);
            uint4 b = *(uint4*)(xb + rr * 64 + off + 16);
            *(uint4*)(h1f + (long)gm * 64 + off)      = a;
            *(uint4*)(h1f + (long)gm * 64 + off + 16) = b;
        }
    }
}

// ---------------- Layer 1 fused: spmm1(fp8, 4-deep gather) + bias + ReLU + gemm2 ----------------
// 2 nodes/wave x 4 edge-slots x 8 feature-lanes; per round 4 records
// loaded branch-free (OOB clamped to p, weight zeroed) -> 4 gathers in flight.
__global__ __launch_bounds__(256) void k_l1(const int* __restrict__ start,
                                            const int2* __restrict__ edges,
                                            const unsigned char* __restrict__ h1f,
                                            const float* __restrict__ b1,
                                            const float* __restrict__ W2,
                                            unsigned short* __restrict__ h2b) {
    __shared__ float w2s[NH * NC];           // 4 KB
    const int tid = threadIdx.x;
    const float4 w2stage = *(const float4*)(W2 + tid * 4);   // 256 x 4 = 1024 floats

    const int lane = tid & 63;
    const int wid  = ((blockIdx.x * 256 + tid) >> 6) * 2 + (lane >> 5);  // 2 nodes/wave
    const int fo   = lane & 7;               // feature octet
    const int es   = (lane >> 3) & 3;        // edge slot (0..3)

    const int s = start[wid], e = start[wid + 1];
    float a[8] = {0.f, 0.f, 0.f, 0.f, 0.f, 0.f, 0.f, 0.f};
    int p = s + es;
    while (p < e) {
        const int i1 = p + 4, i2 = p + 8, i3 = p + 12;
        const bool b1c = i1 < e, b2c = i2 < e, b3c = i3 < e;
        const int2 r0 = edges[p];
        const int2 r1 = edges[b1c ? i1 : p];
        const int2 r2 = edges[b2c ? i2 : p];
        const int2 r3 = edges[b3c ? i3 : p];
        const uint2 v0 = *(const uint2*)(h1f + (long)r0.x * 64 + fo * 8);
        const uint2 v1 = *(const uint2*)(h1f + (long)r1.x * 64 + fo * 8);
        const uint2 v2 = *(const uint2*)(h1f + (long)r2.x * 64 + fo * 8);
        const uint2 v3 = *(const uint2*)(h1f + (long)r3.x * 64 + fo * 8);
        acc_fp8x8(a, v0, __int_as_float(r0.y));
        acc_fp8x8(a, v1, b1c ? __int_as_float(r1.y) : 0.f);
        acc_fp8x8(a, v2, b2c ? __int_as_float(r2.y) : 0.f);
        acc_fp8x8(a, v3, b3c ? __int_as_float(r3.y) : 0.f);
        p += 16;
    }
    // W2 -> LDS (deferred staging: hidden under the gather loop)
    *(float4*)(w2s + tid * 4) = w2stage;
    __syncthreads();
    // reduce over the 4 edge slots (xor 8,16: stays within the 32-lane node group)
#pragma unroll
    for (int m = 8; m <= 16; m <<= 1)
#pragma unroll
        for (int j = 0; j < 8; ++j) a[j] += __shfl_xor(a[j], m, 64);
    // bias + ReLU (all lanes hold full sums of their feature octet)
    const float4 ba = *(const float4*)(b1 + fo * 8);
    const float4 bb = *(const float4*)(b1 + fo * 8 + 4);
    float r[8];
    r[0] = fmaxf(a[0] + ba.x, 0.f); r[1] = fmaxf(a[1] + ba.y, 0.f);
    r[2] = fmaxf(a[2] + ba.z, 0.f); r[3] = fmaxf(a[3] + ba.w, 0.f);
    r[4] = fmaxf(a[4] + bb.x, 0.f); r[5] = fmaxf(a[5] + bb.y, 0.f);
    r[6] = fmaxf(a[6] + bb.z, 0.f); r[7] = fmaxf(a[7] + bb.w, 0.f);
    // fused gemm2: this lane contributes its 8 features to outputs es*4..es*4+3
    float p0 = 0.f, p1 = 0.f, p2 = 0.f, p3 = 0.f;
#pragma unroll
    for (int j = 0; j < 8; ++j) {
        const f32x4 wv = *(const f32x4*)(w2s + (fo * 8 + j) * NC + es * 4);
        p0 += r[j] * wv[0]; p1 += r[j] * wv[1];
        p2 += r[j] * wv[2]; p3 += r[j] * wv[3];
    }
    // reduce over the 8 feature lanes (xor 1,2,4)
#pragma unroll
    for (int m = 1; m <= 4; m <<= 1) {
        p0 += __shfl_xor(p0, m, 64); p1 += __shfl_xor(p1, m, 64);
        p2 += __shfl_xor(p2, m, 64); p3 += __shfl_xor(p3, m, 64);
    }
    if (fo == 0) {
        uint2 pk;
        pk.x = pkbf(p0, p1);
        pk.y = pkbf(p2, p3);
        *(uint2*)(h2b + (long)wid * NC + es * 4) = pk;
    }
}

// ---------------- SpMM2 + bias: 4 nodes/wave x 4 edge-slots, 4-deep gather ----------------
__global__ __launch_bounds__(256) void k_spmm2(const int* __restrict__ start,
                                               const int2* __restrict__ edges,
                                               const unsigned short* __restrict__ h2b,
                                               const float* __restrict__ b2,
                                               float* __restrict__ out) {
    const int lane = threadIdx.x & 63;
    const int wid  = ((blockIdx.x * 256 + threadIdx.x) >> 6) * 4 + (lane >> 4);  // 4 nodes/wave
    const int es   = (lane >> 2) & 3;        // edge slot (0..3)
    const int f4   = lane & 3;               // feature quad
    const int s = start[wid], e = start[wid + 1];
    float4 acc = make_float4(0.f, 0.f, 0.f, 0.f);
    int p = s + es;
    while (p < e) {
        const int i1 = p + 4, i2 = p + 8, i3 = p + 12;
        const bool b1c = i1 < e, b2c = i2 < e, b3c = i3 < e;
        const int2 r0 = edges[p];
        const int2 r1 = edges[b1c ? i1 : p];
        const int2 r2 = edges[b2c ? i2 : p];
        const int2 r3 = edges[b3c ? i3 : p];
        const uint2 v0 = *(const uint2*)(h2b + (long)r0.x * NC + f4 * 4);
        const uint2 v1 = *(const uint2*)(h2b + (long)r1.x * NC + f4 * 4);
        const uint2 v2 = *(const uint2*)(h2b + (long)r2.x * NC + f4 * 4);
        const uint2 v3 = *(const uint2*)(h2b + (long)r3.x * NC + f4 * 4);
        const float w0 = __int_as_float(r0.y);
        const float w1 = b1c ? __int_as_float(r1.y) : 0.f;
        const float w2 = b2c ? __int_as_float(r2.y) : 0.f;
        const float w3 = b3c ? __int_as_float(r3.y) : 0.f;
        acc.x += w0 * bfbits_lo(v0.x); acc.y += w0 * bfbits_hi(v0.x);
        acc.z += w0 * bfbits_lo(v0.y); acc.w += w0 * bfbits_hi(v0.y);
        acc.x += w1 * bfbits_lo(v1.x); acc.y += w1 * bfbits_hi(v1.x);
        acc.z += w1 * bfbits_lo(v1.y); acc.w += w1 * bfbits_hi(v1.y);
        acc.x += w2 * bfbits_lo(v2.x); acc.y += w2 * bfbits_hi(v2.x);
        acc.z += w2 * bfbits_lo(v2.y); acc.w += w2 * bfbits_hi(v2.y);
        acc.x += w3 * bfbits_lo(v3.x); acc.y += w3 * bfbits_hi(v3.x);
        acc.z += w3 * bfbits_lo(v3.y); acc.w += w3 * bfbits_hi(v3.y);
        p += 16;
    }
    // reduce over the 4 edge slots (xor 4,8: stays within the 16-lane node group)
#pragma unroll
    for (int m = 4; m <= 8; m <<= 1) {
        acc.x += __shfl_xor(acc.x, m, 64); acc.y += __shfl_xor(acc.y, m, 64);
        acc.z += __shfl_xor(acc.z, m, 64); acc.w += __shfl_xor(acc.w, m, 64);
    }
    if (es == 0) {
        const float4 b = *(const float4*)(b2 + f4 * 4);
        float4 r;
        r.x = acc.x + b.x; r.y = acc.y + b.y;
        r.z = acc.z + b.z; r.w = acc.w + b.w;
        *(float4*)(out + (long)wid * NC + f4 * 4) = r;
    }
}

extern "C" void kernel_launch(void* const* d_in, const int* in_sizes, int n_in,
                              void* d_out, int out_size, void* d_ws, size_t ws_size,
                              hipStream_t stream) {
    const float* x   = (const float*)d_in[0];
    const float* W1  = (const float*)d_in[1];
    const float* b1  = (const float*)d_in[2];
    const float* W2  = (const float*)d_in[3];
    const float* b2  = (const float*)d_in[4];
    const float* ew  = (const float*)d_in[5];
    const int*   src = (const int*)d_in[6];
    const int*   dst = (const int*)d_in[7];
    float* out = (float*)d_out;

    // workspace layout (<40 MB)
    char* w = (char*)d_ws;
    unsigned char*  h1f = (unsigned char*)(w + 0);           // 6.4 MB fp8 x@W1
    unsigned short* h2b = (unsigned short*)(w + 25600000);   // 3.2 MB bf16 (relu layer1)@W2
    int*   bsum   = (int*) (w + 32000000);                   // 98 ints
    int*   startp = (int*) (w + 32001024);                   // 100001 ints
    int*   cursor = (int*) (w + 32402048);                   // 100000 ints (deg -> cursor)
    int2*  edges  = (int2*)(w + 32803072);                   // 6.4 MB (src, w) records

    k_zero  <<<(NN / 4 + 255) / 256, 256, 0, stream>>>((int4*)cursor);
    k_hist  <<<(NE + 255) / 256, 256, 0, stream>>>(dst, cursor);
    k_scanA <<<SCAN_B, 1024, 0, stream>>>(cursor, bsum);
    k_scanC <<<SCAN_B, 1024, 0, stream>>>(cursor, bsum, startp, cursor);
    k_g1    <<<G1TILES + ROLEB, 256, 0, stream>>>(x, W1, h1f, src, dst, ew, cursor, edges);
    k_l1    <<<(NN / 2 * 64) / 256, 256, 0, stream>>>(startp, edges, h1f, b1, W2, h2b);
    k_spmm2 <<<(NN / 4 * 64) / 256, 256, 0, stream>>>(startp, edges, h2b, b2, out);
}

// Round 21
// 152.970 us; speedup vs baseline: 1.0523x; 1.0027x over previous
//
#include <hip/hip_runtime.h>

#define NN 100000   // nodes
#define NE 800000   // edges
#define NF 500      // in features
#define NH 64       // hidden
#define NC 16       // classes
#define SCAN_B 98   // 98 * 1024 >= NN
#define G1TILES 782 // ceil(100000/128)
#define ROLEB 224   // scatter role blocks fused into k_g1

typedef __attribute__((ext_vector_type(4))) float f32x4;
typedef __attribute__((ext_vector_type(8))) short bf16x8;  // 8 bf16 (4 VGPRs)

// raw RNE fp32->bf16 (proven; ~4 VALU, no NaN-canonicalization branch)
__device__ __forceinline__ unsigned int f2bf(float f) {
    union { float f; unsigned int u; } v; v.f = f;
    return (v.u + 0x7FFFu + ((v.u >> 16) & 1u)) >> 16;   // RNE
}
__device__ __forceinline__ unsigned int pkbf(float a, float b) {
    return f2bf(a) | (f2bf(b) << 16);
}
__device__ __forceinline__ float bfbits_lo(unsigned int u) { return __uint_as_float(u << 16); }
__device__ __forceinline__ float bfbits_hi(unsigned int u) { return __uint_as_float(u & 0xffff0000u); }

// async HBM->LDS, 16B per lane; LDS dest = wave-uniform base + lane*16 (linear)
#define GLOAD_LDS16(g, l) __builtin_amdgcn_global_load_lds(                      \
    (const __attribute__((address_space(1))) void*)(g),                          \
    (__attribute__((address_space(3))) void*)(l), 16, 0, 0)

// decode 8 fp8(e4m3) bytes of v, FMA into a[0..7] with weight w
__device__ __forceinline__ void acc_fp8x8(float* a, const uint2 v, const float w) {
    a[0] += w * __builtin_amdgcn_cvt_f32_fp8(v.x, 0);
    a[1] += w * __builtin_amdgcn_cvt_f32_fp8(v.x, 1);
    a[2] += w * __builtin_amdgcn_cvt_f32_fp8(v.x, 2);
    a[3] += w * __builtin_amdgcn_cvt_f32_fp8(v.x, 3);
    a[4] += w * __builtin_amdgcn_cvt_f32_fp8(v.y, 0);
    a[5] += w * __builtin_amdgcn_cvt_f32_fp8(v.y, 1);
    a[6] += w * __builtin_amdgcn_cvt_f32_fp8(v.y, 2);
    a[7] += w * __builtin_amdgcn_cvt_f32_fp8(v.y, 3);
}

// ---------------- zero cursor/deg ----------------
__global__ __launch_bounds__(256) void k_zero(int4* __restrict__ p) {
    int i = blockIdx.x * 256 + threadIdx.x;          // 25000 int4 = 100000 ints
    if (i < NN / 4) p[i] = make_int4(0, 0, 0, 0);
}

// ---------------- degree histogram: int4-vectorized dst reads ----------------
__global__ void k_hist(const int4* __restrict__ dst4, int* __restrict__ deg) {
    int e = blockIdx.x * 256 + threadIdx.x;          // 200000 int4 records
    if (e < NE / 4) {
        int4 d = dst4[e];
        atomicAdd(&deg[d.x], 1);
        atomicAdd(&deg[d.y], 1);
        atomicAdd(&deg[d.z], 1);
        atomicAdd(&deg[d.w], 1);
    }
}

// ---------------- scan stage A: per-block sums (wave shfl reduce, 1 barrier) ----------------
__global__ __launch_bounds__(1024) void k_scanA(const int* __restrict__ deg, int* __restrict__ bsum) {
    __shared__ int ws[16];
    const int t = threadIdx.x, i = blockIdx.x * 1024 + t;
    const int lane = t & 63, wv = t >> 6;
    int v = (i < NN) ? deg[i] : 0;
#pragma unroll
    for (int m = 1; m <= 32; m <<= 1) v += __shfl_xor(v, m, 64);
    if (lane == 0) ws[wv] = v;
    __syncthreads();
    if (t == 0) {
        int s = 0;
#pragma unroll
        for (int k = 0; k < 16; ++k) s += ws[k];
        bsum[blockIdx.x] = s;
    }
}

// ---------------- scan stage C: wave shfl scan + masked base-reduce (2 barriers) ----------------
__global__ __launch_bounds__(1024) void k_scanC(const int* __restrict__ deg, const int* __restrict__ bsum,
                                                int* __restrict__ start, int* __restrict__ cursor) {
    __shared__ int ws[16];
    __shared__ int sbase;
    const int t = threadIdx.x, b = blockIdx.x;
    const int i = b * 1024 + t;
    const int lane = t & 63, wv = t >> 6;
    const int d = (i < NN) ? deg[i] : 0;
    // wave-level inclusive scan of d
    int x = d;
#pragma unroll
    for (int off = 1; off < 64; off <<= 1) {
        int u = __shfl_up(x, off, 64);
        if (lane >= off) x += u;
    }
    if (lane == 63) ws[wv] = x;
    // base = sum of bsum[0..b-1] (wave 0, masked 2-elem-per-lane reduce over <=97 entries)
    if (wv == 0) {
        int v = (lane < b) ? bsum[lane] : 0;
        if (lane + 64 < b) v += bsum[lane + 64];
#pragma unroll
        for (int m = 1; m <= 32; m <<= 1) v += __shfl_xor(v, m, 64);
        if (lane == 0) sbase = v;
    }
    __syncthreads();
    // per-wave prefix via broadcast LDS reads (no barrier needed after)
    int wpre = 0;
    for (int k = 0; k < wv; ++k) wpre += ws[k];
    const int incl = x + wpre;                       // block-inclusive scan value
    if (i < NN) {
        int ex = sbase + incl - d;                   // global exclusive offset
        start[i] = ex;
        cursor[i] = ex;
    }
    if (b == SCAN_B - 1 && t == 1023) start[NN] = sbase + incl;   // = NE
}

// ---------------- GEMM1 (full, MFMA bf16) + fused SCATTER role; fp8 h1 out ----------------
__global__ __launch_bounds__(256) void k_g1(const float* __restrict__ x,
                                            const float* __restrict__ W1,
                                            unsigned char* __restrict__ h1f,
                                            const int* __restrict__ src, const int* __restrict__ dst,
                                            const float* __restrict__ ew,
                                            int* __restrict__ cursor, int2* __restrict__ edges) {
    __shared__ float xs[128 * 64];           // 32 KB fp32 (reused as fp8 staging in epilogue)
    __shared__ unsigned short ws[64 * 64];   // 8 KB bf16
    const int bid = blockIdx.x, tid = threadIdx.x;
    if (bid >= G1TILES) {                    // scatter role (CSR cursors ready before launch)
        int rb = bid - G1TILES;
        for (int e = rb * 256 + tid; e < NE; e += ROLEB * 256) {
            int p = atomicAdd(&cursor[dst[e]], 1);
            edges[p] = make_int2(src[e], __float_as_int(ew[e]));
        }
        return;
    }
    const int lane = tid & 63;
    const int wv   = tid >> 6;
    const int row0 = bid * 128;

    f32x4 acc[2][4];
#pragma unroll
    for (int i = 0; i < 2; ++i)
#pragma unroll
        for (int j = 0; j < 4; ++j) acc[i][j] = (f32x4){0.f, 0.f, 0.f, 0.f};

    const int lr    = lane >> 4;         // row within issue group (0..3)
    const int lsl   = (lane & 15) >> 1;  // 8-float slot (0..7)
    const int lhalf = lane & 1;          // half-slot (0..1)
    const long maxidx = (long)NN * NF - 4;

    for (int kt = 0; kt < 8; ++kt) {
        const int k0 = kt * 64;
#pragma unroll
        for (int i = 0; i < 8; ++i) {
            int r  = wv * 32 + i * 4 + lr;
            int gm = row0 + r; if (gm >= NN) gm = NN - 1;
            long gi = (long)gm * NF + k0 + ((lsl ^ (r & 7)) << 3) + (lhalf << 2);
            if (gi > maxidx) gi = maxidx;                    // clamp; values killed by W=0
            GLOAD_LDS16(x + gi, xs + (wv * 32 + i * 4) * 64);
        }
#pragma unroll
        for (int p = 0; p < 2; ++p) {
            int u  = tid + p * 256;
            int n  = u & 63, sl = u >> 6;
            int gk = k0 + sl * 8;
            float e[8];
#pragma unroll
            for (int j = 0; j < 8; ++j)
                e[j] = (gk + j < NF) ? W1[(long)(gk + j) * NH + n] : 0.f;
            uint4 pk;
            pk.x = pkbf(e[0], e[1]);
            pk.y = pkbf(e[2], e[3]);
            pk.z = pkbf(e[4], e[5]);
            pk.w = pkbf(e[6], e[7]);
            *(uint4*)(ws + n * 64 + (sl ^ (n & 7)) * 8) = pk;
        }
        __syncthreads();
#pragma unroll
        for (int ks = 0; ks < 2; ++ks) {
            const int kg = ks * 4 + (lane >> 4);
            bf16x8 af[2], bfr[4];
#pragma unroll
            for (int i = 0; i < 2; ++i) {
                int r = wv * 32 + i * 16 + (lane & 15);
                const float* srcp = xs + r * 64 + ((kg ^ (r & 7)) << 3);
                f32x4 lo = *(const f32x4*)(srcp);
                f32x4 hi = *(const f32x4*)(srcp + 4);
                uint4 pk;
                pk.x = pkbf(lo[0], lo[1]);
                pk.y = pkbf(lo[2], lo[3]);
                pk.z = pkbf(hi[0], hi[1]);
                pk.w = pkbf(hi[2], hi[3]);
                af[i] = *(bf16x8*)&pk;
            }
#pragma unroll
            for (int j = 0; j < 4; ++j) {
                int n = j * 16 + (lane & 15);
                bfr[j] = *(const bf16x8*)(ws + n * 64 + (kg ^ (n & 7)) * 8);
            }
#pragma unroll
            for (int i = 0; i < 2; ++i)
#pragma unroll
                for (int j = 0; j < 4; ++j)
                    acc[i][j] = __builtin_amdgcn_mfma_f32_16x16x32_bf16(af[i], bfr[j], acc[i][j], 0, 0, 0);
        }
        __syncthreads();
    }
    // epilogue: fp8(e4m3) rows staged via LDS (xs reused), then coalesced 16B stores
    unsigned char* xb = (unsigned char*)xs;
    const int c = lane & 15;
#pragma unroll
    for (int i = 0; i < 2; ++i) {
#pragma unroll
        for (int q = 0; q < 4; ++q) {
            int r = wv * 32 + i * 16 + (lane >> 4) * 4 + q;   // row within tile
            int pk01 = __builtin_amdgcn_cvt_pk_fp8_f32(acc[i][0][q], acc[i][1][q], 0, false);
            int pk23 = __builtin_amdgcn_cvt_pk_fp8_f32(acc[i][2][q], acc[i][3][q], 0, false);
            xb[r * 64 + 0 * 16 + c] = (unsigned char)(pk01 & 0xff);
            xb[r * 64 + 1 * 16 + c] = (unsigned char)((pk01 >> 8) & 0xff);
            xb[r * 64 + 2 * 16 + c] = (unsigned char)(pk23 & 0xff);
            xb[r * 64 + 3 * 16 + c] = (unsigned char)((pk23 >> 8) & 0xff);
        }
    }
    __syncthreads();
    {
        int rr = tid >> 1, off = (tid & 1) * 32;
        int gm = row0 + rr;
        if (gm < NN) {
            uint4 a = *(uint4*)(xb + rr * 64 + off);
            uint4 b = *(uint4*)(xb + rr * 64 + off + 16);
            *(uint4*)(h1f + (long)gm * 64 + off)      = a;
            *(uint4*)(h1f + (long)gm * 64 + off + 16) = b;
        }
    }
}

// ---------------- Layer 1 fused: spmm1(fp8, 4-deep gather) + bias + ReLU + gemm2 ----------------
// 2 nodes/wave x 4 edge-slots x 8 feature-lanes; per round 4 records
// loaded branch-free (OOB clamped to p, weight zeroed) -> 4 gathers in flight.
__global__ __launch_bounds__(256) void k_l1(const int* __restrict__ start,
                                            const int2* __restrict__ edges,
                                            const unsigned char* __restrict__ h1f,
                                            const float* __restrict__ b1,
                                            const float* __restrict__ W2,
                                            unsigned short* __restrict__ h2b) {
    __shared__ float w2s[NH * NC];           // 4 KB
    const int tid = threadIdx.x;
    const float4 w2stage = *(const float4*)(W2 + tid * 4);   // 256 x 4 = 1024 floats

    const int lane = tid & 63;
    const int wid  = ((blockIdx.x * 256 + tid) >> 6) * 2 + (lane >> 5);  // 2 nodes/wave
    const int fo   = lane & 7;               // feature octet
    const int es   = (lane >> 3) & 3;        // edge slot (0..3)

    const int s = start[wid], e = start[wid + 1];
    float a[8] = {0.f, 0.f, 0.f, 0.f, 0.f, 0.f, 0.f, 0.f};
    int p = s + es;
    while (p < e) {
        const int i1 = p + 4, i2 = p + 8, i3 = p + 12;
        const bool b1c = i1 < e, b2c = i2 < e, b3c = i3 < e;
        const int2 r0 = edges[p];
        const int2 r1 = edges[b1c ? i1 : p];
        const int2 r2 = edges[b2c ? i2 : p];
        const int2 r3 = edges[b3c ? i3 : p];
        const uint2 v0 = *(const uint2*)(h1f + (long)r0.x * 64 + fo * 8);
        const uint2 v1 = *(const uint2*)(h1f + (long)r1.x * 64 + fo * 8);
        const uint2 v2 = *(const uint2*)(h1f + (long)r2.x * 64 + fo * 8);
        const uint2 v3 = *(const uint2*)(h1f + (long)r3.x * 64 + fo * 8);
        acc_fp8x8(a, v0, __int_as_float(r0.y));
        acc_fp8x8(a, v1, b1c ? __int_as_float(r1.y) : 0.f);
        acc_fp8x8(a, v2, b2c ? __int_as_float(r2.y) : 0.f);
        acc_fp8x8(a, v3, b3c ? __int_as_float(r3.y) : 0.f);
        p += 16;
    }
    // W2 -> LDS (deferred staging: hidden under the gather loop)
    *(float4*)(w2s + tid * 4) = w2stage;
    __syncthreads();
    // reduce over the 4 edge slots (xor 8,16: stays within the 32-lane node group)
#pragma unroll
    for (int m = 8; m <= 16; m <<= 1)
#pragma unroll
        for (int j = 0; j < 8; ++j) a[j] += __shfl_xor(a[j], m, 64);
    // bias + ReLU (all lanes hold full sums of their feature octet)
    const float4 ba = *(const float4*)(b1 + fo * 8);
    const float4 bb = *(const float4*)(b1 + fo * 8 + 4);
    float r[8];
    r[0] = fmaxf(a[0] + ba.x, 0.f); r[1] = fmaxf(a[1] + ba.y, 0.f);
    r[2] = fmaxf(a[2] + ba.z, 0.f); r[3] = fmaxf(a[3] + ba.w, 0.f);
    r[4] = fmaxf(a[4] + bb.x, 0.f); r[5] = fmaxf(a[5] + bb.y, 0.f);
    r[6] = fmaxf(a[6] + bb.z, 0.f); r[7] = fmaxf(a[7] + bb.w, 0.f);
    // fused gemm2: this lane contributes its 8 features to outputs es*4..es*4+3
    float p0 = 0.f, p1 = 0.f, p2 = 0.f, p3 = 0.f;
#pragma unroll
    for (int j = 0; j < 8; ++j) {
        const f32x4 wv = *(const f32x4*)(w2s + (fo * 8 + j) * NC + es * 4);
        p0 += r[j] * wv[0]; p1 += r[j] * wv[1];
        p2 += r[j] * wv[2]; p3 += r[j] * wv[3];
    }
    // reduce over the 8 feature lanes (xor 1,2,4)
#pragma unroll
    for (int m = 1; m <= 4; m <<= 1) {
        p0 += __shfl_xor(p0, m, 64); p1 += __shfl_xor(p1, m, 64);
        p2 += __shfl_xor(p2, m, 64); p3 += __shfl_xor(p3, m, 64);
    }
    if (fo == 0) {
        uint2 pk;
        pk.x = pkbf(p0, p1);
        pk.y = pkbf(p2, p3);
        *(uint2*)(h2b + (long)wid * NC + es * 4) = pk;
    }
}

// ---------------- SpMM2 + bias: 4 nodes/wave x 4 edge-slots, 4-deep gather ----------------
__global__ __launch_bounds__(256) void k_spmm2(const int* __restrict__ start,
                                               const int2* __restrict__ edges,
                                               const unsigned short* __restrict__ h2b,
                                               const float* __restrict__ b2,
                                               float* __restrict__ out) {
    const int lane = threadIdx.x & 63;
    const int wid  = ((blockIdx.x * 256 + threadIdx.x) >> 6) * 4 + (lane >> 4);  // 4 nodes/wave
    const int es   = (lane >> 2) & 3;        // edge slot (0..3)
    const int f4   = lane & 3;               // feature quad
    const int s = start[wid], e = start[wid + 1];
    float4 acc = make_float4(0.f, 0.f, 0.f, 0.f);
    int p = s + es;
    while (p < e) {
        const int i1 = p + 4, i2 = p + 8, i3 = p + 12;
        const bool b1c = i1 < e, b2c = i2 < e, b3c = i3 < e;
        const int2 r0 = edges[p];
        const int2 r1 = edges[b1c ? i1 : p];
        const int2 r2 = edges[b2c ? i2 : p];
        const int2 r3 = edges[b3c ? i3 : p];
        const uint2 v0 = *(const uint2*)(h2b + (long)r0.x * NC + f4 * 4);
        const uint2 v1 = *(const uint2*)(h2b + (long)r1.x * NC + f4 * 4);
        const uint2 v2 = *(const uint2*)(h2b + (long)r2.x * NC + f4 * 4);
        const uint2 v3 = *(const uint2*)(h2b + (long)r3.x * NC + f4 * 4);
        const float w0 = __int_as_float(r0.y);
        const float w1 = b1c ? __int_as_float(r1.y) : 0.f;
        const float w2 = b2c ? __int_as_float(r2.y) : 0.f;
        const float w3 = b3c ? __int_as_float(r3.y) : 0.f;
        acc.x += w0 * bfbits_lo(v0.x); acc.y += w0 * bfbits_hi(v0.x);
        acc.z += w0 * bfbits_lo(v0.y); acc.w += w0 * bfbits_hi(v0.y);
        acc.x += w1 * bfbits_lo(v1.x); acc.y += w1 * bfbits_hi(v1.x);
        acc.z += w1 * bfbits_lo(v1.y); acc.w += w1 * bfbits_hi(v1.y);
        acc.x += w2 * bfbits_lo(v2.x); acc.y += w2 * bfbits_hi(v2.x);
        acc.z += w2 * bfbits_lo(v2.y); acc.w += w2 * bfbits_hi(v2.y);
        acc.x += w3 * bfbits_lo(v3.x); acc.y += w3 * bfbits_hi(v3.x);
        acc.z += w3 * bfbits_lo(v3.y); acc.w += w3 * bfbits_hi(v3.y);
        p += 16;
    }
    // reduce over the 4 edge slots (xor 4,8: stays within the 16-lane node group)
#pragma unroll
    for (int m = 4; m <= 8; m <<= 1) {
        acc.x += __shfl_xor(acc.x, m, 64); acc.y += __shfl_xor(acc.y, m, 64);
        acc.z += __shfl_xor(acc.z, m, 64); acc.w += __shfl_xor(acc.w, m, 64);
    }
    if (es == 0) {
        const float4 b = *(const float4*)(b2 + f4 * 4);
        float4 r;
        r.x = acc.x + b.x; r.y = acc.y + b.y;
        r.z = acc.z + b.z; r.w = acc.w + b.w;
        *(float4*)(out + (long)wid * NC + f4 * 4) = r;
    }
}

extern "C" void kernel_launch(void* const* d_in, const int* in_sizes, int n_in,
                              void* d_out, int out_size, void* d_ws, size_t ws_size,
                              hipStream_t stream) {
    const float* x   = (const float*)d_in[0];
    const float* W1  = (const float*)d_in[1];
    const float* b1  = (const float*)d_in[2];
    const float* W2  = (const float*)d_in[3];
    const float* b2  = (const float*)d_in[4];
    const float* ew  = (const float*)d_in[5];
    const int*   src = (const int*)d_in[6];
    const int*   dst = (const int*)d_in[7];
    float* out = (float*)d_out;

    // workspace layout (<40 MB)
    char* w = (char*)d_ws;
    unsigned char*  h1f = (unsigned char*)(w + 0);           // 6.4 MB fp8 x@W1
    unsigned short* h2b = (unsigned short*)(w + 25600000);   // 3.2 MB bf16 (relu layer1)@W2
    int*   bsum   = (int*) (w + 32000000);                   // 98 ints
    int*   startp = (int*) (w + 32001024);                   // 100001 ints
    int*   cursor = (int*) (w + 32402048);                   // 100000 ints (deg -> cursor)
    int2*  edges  = (int2*)(w + 32803072);                   // 6.4 MB (src, w) records

    k_zero  <<<(NN / 4 + 255) / 256, 256, 0, stream>>>((int4*)cursor);
    k_hist  <<<(NE / 4 + 255) / 256, 256, 0, stream>>>((const int4*)dst, cursor);
    k_scanA <<<SCAN_B, 1024, 0, stream>>>(cursor, bsum);
    k_scanC <<<SCAN_B, 1024, 0, stream>>>(cursor, bsum, startp, cursor);
    k_g1    <<<G1TILES + ROLEB, 256, 0, stream>>>(x, W1, h1f, src, dst, ew, cursor, edges);
    k_l1    <<<(NN / 2 * 64) / 256, 256, 0, stream>>>(startp, edges, h1f, b1, W2, h2b);
    k_spmm2 <<<(NN / 4 * 64) / 256, 256, 0, stream>>>(startp, edges, h2b, b2, out);
}